// Round 5
// baseline (844.781 us; speedup 1.0000x reference)
//
#include <hip/hip_runtime.h>
#include <hip/hip_cooperative_groups.h>

namespace cg = cooperative_groups;

#define BB 2
#define SS 4096
#define DM 768
#define NH 12
#define OUTC 512
#define QSCALE 0.125f

struct P {
  const float *x, *wqg, *bqg, *wkg, *bkg, *wvg, *bvg, *wo, *bo, *wp, *bp, *wfc, *bfc;
  float *qpart, *qg, *qb, *l, *qw, *part, *out0acc, *attnraw, *pooledraw, *out;
};

__device__ __forceinline__ float wave_sum64(float v) {
#pragma unroll
  for (int o = 32; o > 0; o >>= 1) v += __shfl_xor(v, o, 64);
  return v;
}

// One cooperative kernel, 512 blocks x 256 threads (2 blocks/CU guaranteed
// resident: ~10KB LDS, <128 VGPR). Stages separated by grid.sync().
__global__ __launch_bounds__(256) void kFused(P p) {
  cg::grid_group grid = cg::this_grid();
  const int blk = blockIdx.x;
  const int t = threadIdx.x, lane = t & 63, w = t >> 6;
  __shared__ float sh[2560];   // 10 KB, re-purposed per stage

  // ---- S1: qpart[b,h,js][d] = sum_{j in 96-slice} x[b,0,j]*wqg[j,h*64+d];
  //          block 192 zeroes the 4608-float accumulator region.
  if (blk < 192) {
    int h = blk % 12, r = blk / 12, b = r & 1, js = r >> 1;
    float* x0 = sh; float* red = sh + 96;
    if (t < 96) x0[t] = p.x[(size_t)b*SS*DM + js*96 + t];
    __syncthreads();
    float acc = 0.f;
    for (int k = 0; k < 24; ++k)
      acc += x0[w*24 + k] * p.wqg[(size_t)(js*96 + w*24 + k)*DM + h*64 + lane];
    red[w*64 + lane] = acc;
    __syncthreads();
    if (t < 64)
      p.qpart[(((size_t)b*NH + h)*8 + js)*64 + t] =
          red[t] + red[64+t] + red[128+t] + red[192+t];
  } else if (blk == 192) {
    for (int i = t; i < 3*DM*BB; i += 256) p.out0acc[i] = 0.f;  // out0acc+attnraw+pooledraw
  }
  __threadfence(); grid.sync();

  // ---- S2: qg = (sum qpart + bqg)*scale; qb = qg.bkg; l = 0
  if (blk < 24 && t < 64) {
    int h = blk % 12, b = blk / 12;
    float s = 0.f;
#pragma unroll
    for (int js = 0; js < 8; ++js)
      s += p.qpart[(((size_t)b*NH + h)*8 + js)*64 + t];
    float qgv = (s + p.bqg[h*64 + t]) * QSCALE;
    p.qg[((size_t)b*NH + h)*64 + t] = qgv;
    float qbv = wave_sum64(qgv * p.bkg[h*64 + t]);
    if (t == 0) { p.qb[b*NH + h] = qbv; p.l[b*NH + h] = 0.f; }
  }
  __threadfence(); grid.sync();

  // ---- S3: qw[b,h,j] = qg[b,h,:] . wkg[j, h*64:+64]
  if (blk < 72) {
    int h = blk % 12, r = blk / 12, b = r & 1, js3 = r >> 1;
    float4* qg4 = (float4*)sh;
    if (t < 16) qg4[t] = ((const float4*)p.qg)[((size_t)b*NH + h)*16 + t];
    __syncthreads();
    int j = js3*256 + t;
    const float4* wr = (const float4*)p.wkg + (size_t)j*192 + h*16;
    float acc = 0.f;
#pragma unroll
    for (int q = 0; q < 16; ++q) {
      float4 wv = wr[q], qv = qg4[q];
      acc += wv.x*qv.x + wv.y*qv.y + wv.z*qv.z + wv.w*qv.w;
    }
    p.qw[((size_t)b*NH + h)*DM + j] = acc;
  }
  __threadfence(); grid.sync();

  // ---- S4: fused scores+exp+l+weighted-row-sum. Block = (chunk of 64 s) x
  //          (3-head group) x b. All 512 blocks.
  {
    int c = blk & 63, hg = (blk >> 6) & 3, b = blk >> 8;
    float* qwl = sh;            // 2304
    float* pl  = sh + 2304;     // 192
    float* qbl = sh + 2496;     // 3
    const float* qwsrc = p.qw + ((size_t)b*NH + hg*3)*DM;
    for (int i = t; i < 3*DM; i += 256) qwl[i] = qwsrc[i];
    if (t < 3) qbl[t] = p.qb[b*NH + hg*3 + t];
    __syncthreads();
    const size_t xbase = ((size_t)b*SS + (size_t)c*64)*DM;
    const float4* x4 = (const float4*)(p.x + xbase);
    const float4* qw4 = (const float4*)qwl;
    float lacc = 0.f;
#pragma unroll
    for (int batch = 0; batch < 4; ++batch) {
      int sl = w*16 + batch*4;
      float acc[4][3] = {};
#pragma unroll
      for (int k = 0; k < 3; ++k) {
        int jq = k*64 + lane;
        float4 xf[4];
#pragma unroll
        for (int si = 0; si < 4; ++si) xf[si] = x4[(size_t)(sl + si)*192 + jq];
#pragma unroll
        for (int hh = 0; hh < 3; ++hh) {
          float4 qv = qw4[hh*192 + jq];
#pragma unroll
          for (int si = 0; si < 4; ++si)
            acc[si][hh] += xf[si].x*qv.x + xf[si].y*qv.y + xf[si].z*qv.z + xf[si].w*qv.w;
        }
      }
      float preg = 0.f;
#pragma unroll
      for (int si = 0; si < 4; ++si)
#pragma unroll
        for (int hh = 0; hh < 3; ++hh) {
          float r = wave_sum64(acc[si][hh]);
          float pp = __expf(r + qbl[hh]);
          if (lane == hh) lacc += pp;
          if (lane == si*3 + hh) preg = pp;
        }
      if (lane < 12) pl[(sl + lane/3)*3 + (lane % 3)] = preg;
    }
    if (lane < 3) atomicAdd(&p.l[b*NH + hg*3 + lane], lacc);
    __syncthreads();
    // phase 2: partials for 3 heads over this chunk
    float a2[3][3] = {};
    for (int s = 0; s < 64; ++s) {
      float pv0 = pl[s*3], pv1 = pl[s*3+1], pv2 = pl[s*3+2];
      float xv0 = p.x[xbase + (size_t)s*DM + t];
      float xv1 = p.x[xbase + (size_t)s*DM + t + 256];
      float xv2 = p.x[xbase + (size_t)s*DM + t + 512];
      a2[0][0] += pv0*xv0; a2[0][1] += pv0*xv1; a2[0][2] += pv0*xv2;
      a2[1][0] += pv1*xv0; a2[1][1] += pv1*xv1; a2[1][2] += pv1*xv2;
      a2[2][0] += pv2*xv0; a2[2][1] += pv2*xv1; a2[2][2] += pv2*xv2;
    }
    float* dst = p.part + ((size_t)(b*64 + c)*NH + hg*3)*DM;
#pragma unroll
    for (int hh = 0; hh < 3; ++hh)
#pragma unroll
      for (int i = 0; i < 3; ++i) dst[hh*DM + t + 256*i] = a2[hh][i];
  }
  __threadfence(); grid.sync();

  // ---- S5+6: reduce partials over 64 chunks, /l, then out0acc += xwn . wvg
  if (blk < 288) {
    int js = blk % 12, r = blk / 12, h = r % 12, b = r / 12;
    float* red = sh; float* xs = sh + 256;
    float s = 0.f;
    for (int cc = 0; cc < 16; ++cc) {
      int c = w*16 + cc;
      s += p.part[((size_t)(b*64 + c)*NH + h)*DM + js*64 + lane];
    }
    red[w*64 + lane] = s;
    __syncthreads();
    if (t < 64)
      xs[t] = (red[t] + red[64+t] + red[128+t] + red[192+t]) / p.l[b*NH + h];
    __syncthreads();
    float acc = 0.f;
#pragma unroll
    for (int q = 0; q < 16; ++q)
      acc += xs[w*16 + q] * p.wvg[(size_t)(js*64 + w*16 + q)*DM + h*64 + lane];
    red[w*64 + lane] = acc;
    __syncthreads();
    if (t < 64)
      atomicAdd(&p.out0acc[b*DM + h*64 + t],
                red[t] + red[64+t] + red[128+t] + red[192+t]);
  }
  __threadfence(); grid.sync();

  // ---- S7: attnraw[b][c] += sum_j (out0acc[b][j]+bvg[j]) * wo[j][c]
  if (blk < 48) {
    int j0 = blk*16;
    float* xs2 = sh;
    if (t < 32) { int bb = t >> 4, jj = t & 15;
      xs2[t] = p.out0acc[bb*DM + j0 + jj] + p.bvg[j0 + jj]; }
    __syncthreads();
    if (t < 192) {
      float4 a0 = {0,0,0,0}, a1 = {0,0,0,0};
      const float4* W4 = (const float4*)p.wo;
#pragma unroll
      for (int jj = 0; jj < 16; ++jj) {
        float4 wv = W4[(size_t)(j0 + jj)*192 + t];
        float s0 = xs2[jj], s1 = xs2[16 + jj];
        a0.x += s0*wv.x; a0.y += s0*wv.y; a0.z += s0*wv.z; a0.w += s0*wv.w;
        a1.x += s1*wv.x; a1.y += s1*wv.y; a1.z += s1*wv.z; a1.w += s1*wv.w;
      }
      int cc = t*4;
      atomicAdd(&p.attnraw[cc+0], a0.x); atomicAdd(&p.attnraw[cc+1], a0.y);
      atomicAdd(&p.attnraw[cc+2], a0.z); atomicAdd(&p.attnraw[cc+3], a0.w);
      atomicAdd(&p.attnraw[DM+cc+0], a1.x); atomicAdd(&p.attnraw[DM+cc+1], a1.y);
      atomicAdd(&p.attnraw[DM+cc+2], a1.z); atomicAdd(&p.attnraw[DM+cc+3], a1.w);
    }
  }
  __threadfence(); grid.sync();

  // ---- S8: pooledraw[b][c] += sum_j (attnraw[b][j]+bo[j]) * wp[j][c]
  if (blk < 48) {
    int j0 = blk*16;
    float* xs2 = sh;
    if (t < 32) { int bb = t >> 4, jj = t & 15;
      xs2[t] = p.attnraw[bb*DM + j0 + jj] + p.bo[j0 + jj]; }
    __syncthreads();
    if (t < 192) {
      float4 a0 = {0,0,0,0}, a1 = {0,0,0,0};
      const float4* W4 = (const float4*)p.wp;
#pragma unroll
      for (int jj = 0; jj < 16; ++jj) {
        float4 wv = W4[(size_t)(j0 + jj)*192 + t];
        float s0 = xs2[jj], s1 = xs2[16 + jj];
        a0.x += s0*wv.x; a0.y += s0*wv.y; a0.z += s0*wv.z; a0.w += s0*wv.w;
        a1.x += s1*wv.x; a1.y += s1*wv.y; a1.z += s1*wv.z; a1.w += s1*wv.w;
      }
      int cc = t*4;
      atomicAdd(&p.pooledraw[cc+0], a0.x); atomicAdd(&p.pooledraw[cc+1], a0.y);
      atomicAdd(&p.pooledraw[cc+2], a0.z); atomicAdd(&p.pooledraw[cc+3], a0.w);
      atomicAdd(&p.pooledraw[DM+cc+0], a1.x); atomicAdd(&p.pooledraw[DM+cc+1], a1.y);
      atomicAdd(&p.pooledraw[DM+cc+2], a1.z); atomicAdd(&p.pooledraw[DM+cc+3], a1.w);
    }
  }
  __threadfence(); grid.sync();

  // ---- S9: out[b, tile*64+c] = tanh(pooledraw+bp) . wfc[:,c] + bfc  (full write)
  if (blk < 16) {
    int tile = blk & 7, b = blk >> 3;
    float* pl = sh; float* red = sh + 768;
    for (int i = t; i < DM; i += 256) pl[i] = tanhf(p.pooledraw[b*DM + i] + p.bp[i]);
    __syncthreads();
    float acc = 0.f;
    for (int jj = 0; jj < 192; ++jj) {
      int j = w*192 + jj;
      acc += pl[j] * p.wfc[(size_t)j*OUTC + tile*64 + lane];
    }
    red[w*64 + lane] = acc;
    __syncthreads();
    if (t < 64)
      p.out[(size_t)b*OUTC + tile*64 + t] =
          red[t] + red[64+t] + red[128+t] + red[192+t] + p.bfc[tile*64 + t];
  }
}

extern "C" void kernel_launch(void* const* d_in, const int* in_sizes, int n_in,
                              void* d_out, int out_size, void* d_ws, size_t ws_size,
                              hipStream_t stream) {
  float* ws = (float*)d_ws;
  P prm;
  prm.x   = (const float*)d_in[0];
  prm.wqg = (const float*)d_in[7];
  prm.bqg = (const float*)d_in[8];
  prm.wkg = (const float*)d_in[9];
  prm.bkg = (const float*)d_in[10];
  prm.wvg = (const float*)d_in[11];
  prm.bvg = (const float*)d_in[12];
  prm.wo  = (const float*)d_in[13];
  prm.bo  = (const float*)d_in[14];
  prm.wp  = (const float*)d_in[15];
  prm.bp  = (const float*)d_in[16];
  prm.wfc = (const float*)d_in[17];
  prm.bfc = (const float*)d_in[18];
  prm.qpart     = ws;             // 12288
  prm.qg        = ws + 12288;     // 1536
  prm.qb        = ws + 13824;     // 24
  prm.l         = ws + 13856;     // 24
  prm.qw        = ws + 13888;     // 18432
  prm.out0acc   = ws + 32320;     // 1536 ┐
  prm.attnraw   = ws + 33856;     // 1536 │ zeroed contiguously in S1
  prm.pooledraw = ws + 35392;     // 1536 ┘
  prm.part      = ws + 36928;     // 2*64*12*768 = 1179648
  prm.out       = (float*)d_out;

  void* args[] = {&prm};
  hipLaunchCooperativeKernel((void*)kFused, dim3(512), dim3(256), args, 0, stream);
}

// Round 6
// 610.710 us; speedup vs baseline: 1.3833x; 1.3833x over previous
//
#include <hip/hip_runtime.h>

#define BB 2
#define SS 4096
#define DM 768
#define NH 12
#define OUTC 512
#define QSCALE 0.125f
#define NBLK 512
#define INITM 0x13579BDFu

struct P {
  const float *x, *wqg, *bqg, *wkg, *bkg, *wvg, *bvg, *wo, *bo, *wp, *bp, *wfc, *bfc;
  float *qpart, *qb, *l, *qw, *out0acc, *attnraw, *pooledraw, *part, *out;
  unsigned *bar;
};

__device__ __forceinline__ float wave_sum64(float v) {
#pragma unroll
  for (int o = 32; o > 0; o >>= 1) v += __shfl_xor(v, o, 64);
  return v;
}

// Device-scope soft barrier: arrival counter in ws (poisoned each call; init
// block publishes INITM gate after zeroing counters). One counter per barrier
// index, single-use per kernel invocation.
__device__ __forceinline__ void softbar(unsigned* B, int k) {
  __syncthreads();
  if (threadIdx.x == 0) {
    __threadfence();  // release: publish this block's writes (L2 wb)
    while (__hip_atomic_load(&B[0], __ATOMIC_ACQUIRE, __HIP_MEMORY_SCOPE_AGENT) != INITM)
      __builtin_amdgcn_s_sleep(2);
    __hip_atomic_fetch_add(&B[2 + k], 1u, __ATOMIC_ACQ_REL, __HIP_MEMORY_SCOPE_AGENT);
    while (__hip_atomic_load(&B[2 + k], __ATOMIC_ACQUIRE, __HIP_MEMORY_SCOPE_AGENT) < NBLK)
      __builtin_amdgcn_s_sleep(2);
    __threadfence();  // acquire: invalidate local caches
  }
  __syncthreads();
}

__global__ __launch_bounds__(256) void kFused(P p) {
  const int blk = blockIdx.x;
  const int t = threadIdx.x, lane = t & 63, w = t >> 6;
  __shared__ float sh[2560];   // 10 KB, re-purposed per stage

  // ---- init: block 511 zeroes barrier counters, opens the gate
  if (blk == NBLK - 1 && t == 0) {
    for (int k = 0; k < 14; ++k)
      __hip_atomic_store(&p.bar[2 + k], 0u, __ATOMIC_RELEASE, __HIP_MEMORY_SCOPE_AGENT);
    __hip_atomic_store(&p.bar[0], INITM, __ATOMIC_RELEASE, __HIP_MEMORY_SCOPE_AGENT);
  }

  // ---- S1: qpart[b,h,js][d] = sum_{j in 96-slice} x[b,0,j]*wqg[j,h*64+d]
  if (blk < 192) {
    int h = blk % 12, r = blk / 12, b = r & 1, js = r >> 1;
    float* x0 = sh; float* red = sh + 96;
    if (t < 96) x0[t] = p.x[(size_t)b*SS*DM + js*96 + t];
    __syncthreads();
    float acc = 0.f;
    for (int k = 0; k < 24; ++k)
      acc += x0[w*24 + k] * p.wqg[(size_t)(js*96 + w*24 + k)*DM + h*64 + lane];
    red[w*64 + lane] = acc;
    __syncthreads();
    if (t < 64)
      p.qpart[(((size_t)b*NH + h)*8 + js)*64 + t] =
          red[t] + red[64+t] + red[128+t] + red[192+t];
  }
  softbar(p.bar, 0);

  // ---- S2: finalize qg (LDS), qb, l=0; qw[b,h,j] = qg . wkg[j, h-slice];
  //          block 72 zeroes out0acc/attnraw/pooledraw.
  if (blk < 72) {
    int h = blk % 12, rb = blk / 12, b = rb & 1, js3 = rb >> 1;  // js3 in [0,3)
    float* qg = sh;
    if (t < 64) {
      float s = 0.f;
#pragma unroll
      for (int js = 0; js < 8; ++js)
        s += p.qpart[(((size_t)b*NH + h)*8 + js)*64 + t];
      qg[t] = (s + p.bqg[h*64 + t]) * QSCALE;
    }
    __syncthreads();
    if (js3 == 0 && t < 64) {
      float qbv = wave_sum64(qg[t] * p.bkg[h*64 + t]);
      if (t == 0) { p.qb[b*NH + h] = qbv; p.l[b*NH + h] = 0.f; }
    }
    const float4* qg4 = (const float4*)qg;
    int j = js3*256 + t;
    const float4* wr = (const float4*)p.wkg + (size_t)j*192 + h*16;
    float acc = 0.f;
#pragma unroll
    for (int q = 0; q < 16; ++q) {
      float4 wv = wr[q], qv = qg4[q];
      acc += wv.x*qv.x + wv.y*qv.y + wv.z*qv.z + wv.w*qv.w;
    }
    p.qw[((size_t)b*NH + h)*DM + j] = acc;
  } else if (blk == 72) {
    for (int i = t; i < 3*DM*BB; i += 256) p.out0acc[i] = 0.f;
  }
  softbar(p.bar, 1);

  // ---- S3: fused scores+exp+l+weighted-row-sum. Block = chunk(64) x hg(4) x b(2).
  {
    int c = blk & 63, hg = (blk >> 6) & 3, b = blk >> 8;
    float* qwl = sh;            // 2304
    float* pl  = sh + 2304;     // 192
    float* qbl = sh + 2496;     // 3
    const float* qwsrc = p.qw + ((size_t)b*NH + hg*3)*DM;
    for (int i = t; i < 3*DM; i += 256) qwl[i] = qwsrc[i];
    if (t < 3) qbl[t] = p.qb[b*NH + hg*3 + t];
    __syncthreads();
    const size_t xbase = ((size_t)b*SS + (size_t)c*64)*DM;
    const float4* x4 = (const float4*)(p.x + xbase);
    const float4* qw4 = (const float4*)qwl;
    float lacc = 0.f;
#pragma unroll
    for (int batch = 0; batch < 4; ++batch) {
      int sl = w*16 + batch*4;
      float acc[4][3] = {};
#pragma unroll
      for (int k = 0; k < 3; ++k) {
        int jq = k*64 + lane;
        float4 xf[4];
#pragma unroll
        for (int si = 0; si < 4; ++si) xf[si] = x4[(size_t)(sl + si)*192 + jq];
#pragma unroll
        for (int hh = 0; hh < 3; ++hh) {
          float4 qv = qw4[hh*192 + jq];
#pragma unroll
          for (int si = 0; si < 4; ++si)
            acc[si][hh] += xf[si].x*qv.x + xf[si].y*qv.y + xf[si].z*qv.z + xf[si].w*qv.w;
        }
      }
      float preg = 0.f;
#pragma unroll
      for (int si = 0; si < 4; ++si)
#pragma unroll
        for (int hh = 0; hh < 3; ++hh) {
          float r = wave_sum64(acc[si][hh]);
          float pp = __expf(r + qbl[hh]);
          if (lane == hh) lacc += pp;
          if (lane == si*3 + hh) preg = pp;
        }
      if (lane < 12) pl[(sl + lane/3)*3 + (lane % 3)] = preg;
    }
    if (lane < 3) atomicAdd(&p.l[b*NH + hg*3 + lane], lacc);
    __syncthreads();
    float a2[3][3] = {};
    for (int s = 0; s < 64; ++s) {
      float pv0 = pl[s*3], pv1 = pl[s*3+1], pv2 = pl[s*3+2];
      float xv0 = p.x[xbase + (size_t)s*DM + t];
      float xv1 = p.x[xbase + (size_t)s*DM + t + 256];
      float xv2 = p.x[xbase + (size_t)s*DM + t + 512];
      a2[0][0] += pv0*xv0; a2[0][1] += pv0*xv1; a2[0][2] += pv0*xv2;
      a2[1][0] += pv1*xv0; a2[1][1] += pv1*xv1; a2[1][2] += pv1*xv2;
      a2[2][0] += pv2*xv0; a2[2][1] += pv2*xv1; a2[2][2] += pv2*xv2;
    }
    float* dst = p.part + ((size_t)(b*64 + c)*NH + hg*3)*DM;
#pragma unroll
    for (int hh = 0; hh < 3; ++hh)
#pragma unroll
      for (int i = 0; i < 3; ++i) dst[hh*DM + t + 256*i] = a2[hh][i];
  }
  softbar(p.bar, 2);

  // ---- S4: reduce partials over 64 chunks, /l, out0acc += xwn . wvg
  if (blk < 288) {
    int js = blk % 12, r = blk / 12, h = r % 12, b = r / 12;
    float* red = sh; float* xs = sh + 256;
    float s = 0.f;
    for (int cc = 0; cc < 16; ++cc) {
      int c = w*16 + cc;
      s += p.part[((size_t)(b*64 + c)*NH + h)*DM + js*64 + lane];
    }
    red[w*64 + lane] = s;
    __syncthreads();
    if (t < 64)
      xs[t] = (red[t] + red[64+t] + red[128+t] + red[192+t]) / p.l[b*NH + h];
    __syncthreads();
    float acc = 0.f;
#pragma unroll
    for (int q = 0; q < 16; ++q)
      acc += xs[w*16 + q] * p.wvg[(size_t)(js*64 + w*16 + q)*DM + h*64 + lane];
    red[w*64 + lane] = acc;
    __syncthreads();
    if (t < 64)
      atomicAdd(&p.out0acc[b*DM + h*64 + t],
                red[t] + red[64+t] + red[128+t] + red[192+t]);
  }
  softbar(p.bar, 3);

  // ---- S5: attnraw[b][c] += sum_j (out0acc[b][j]+bvg[j]) * wo[j][c]
  if (blk < 48) {
    int j0 = blk*16;
    float* xs2 = sh;
    if (t < 32) { int bb = t >> 4, jj = t & 15;
      xs2[t] = p.out0acc[bb*DM + j0 + jj] + p.bvg[j0 + jj]; }
    __syncthreads();
    if (t < 192) {
      float4 a0 = {0,0,0,0}, a1 = {0,0,0,0};
      const float4* W4 = (const float4*)p.wo;
#pragma unroll
      for (int jj = 0; jj < 16; ++jj) {
        float4 wv = W4[(size_t)(j0 + jj)*192 + t];
        float s0 = xs2[jj], s1 = xs2[16 + jj];
        a0.x += s0*wv.x; a0.y += s0*wv.y; a0.z += s0*wv.z; a0.w += s0*wv.w;
        a1.x += s1*wv.x; a1.y += s1*wv.y; a1.z += s1*wv.z; a1.w += s1*wv.w;
      }
      int cc = t*4;
      atomicAdd(&p.attnraw[cc+0], a0.x); atomicAdd(&p.attnraw[cc+1], a0.y);
      atomicAdd(&p.attnraw[cc+2], a0.z); atomicAdd(&p.attnraw[cc+3], a0.w);
      atomicAdd(&p.attnraw[DM+cc+0], a1.x); atomicAdd(&p.attnraw[DM+cc+1], a1.y);
      atomicAdd(&p.attnraw[DM+cc+2], a1.z); atomicAdd(&p.attnraw[DM+cc+3], a1.w);
    }
  }
  softbar(p.bar, 4);

  // ---- S6: pooledraw[b][c] += sum_j (attnraw[b][j]+bo[j]) * wp[j][c]
  if (blk < 48) {
    int j0 = blk*16;
    float* xs2 = sh;
    if (t < 32) { int bb = t >> 4, jj = t & 15;
      xs2[t] = p.attnraw[bb*DM + j0 + jj] + p.bo[j0 + jj]; }
    __syncthreads();
    if (t < 192) {
      float4 a0 = {0,0,0,0}, a1 = {0,0,0,0};
      const float4* W4 = (const float4*)p.wp;
#pragma unroll
      for (int jj = 0; jj < 16; ++jj) {
        float4 wv = W4[(size_t)(j0 + jj)*192 + t];
        float s0 = xs2[jj], s1 = xs2[16 + jj];
        a0.x += s0*wv.x; a0.y += s0*wv.y; a0.z += s0*wv.z; a0.w += s0*wv.w;
        a1.x += s1*wv.x; a1.y += s1*wv.y; a1.z += s1*wv.z; a1.w += s1*wv.w;
      }
      int cc = t*4;
      atomicAdd(&p.pooledraw[cc+0], a0.x); atomicAdd(&p.pooledraw[cc+1], a0.y);
      atomicAdd(&p.pooledraw[cc+2], a0.z); atomicAdd(&p.pooledraw[cc+3], a0.w);
      atomicAdd(&p.pooledraw[DM+cc+0], a1.x); atomicAdd(&p.pooledraw[DM+cc+1], a1.y);
      atomicAdd(&p.pooledraw[DM+cc+2], a1.z); atomicAdd(&p.pooledraw[DM+cc+3], a1.w);
    }
  }
  softbar(p.bar, 5);

  // ---- S7: out[b, tile*64+c] = tanh(pooledraw+bp) . wfc[:,c] + bfc  (full write)
  if (blk < 16) {
    int tile = blk & 7, b = blk >> 3;
    float* pl = sh; float* red = sh + 768;
    for (int i = t; i < DM; i += 256) pl[i] = tanhf(p.pooledraw[b*DM + i] + p.bp[i]);
    __syncthreads();
    float acc = 0.f;
    for (int jj = 0; jj < 192; ++jj) {
      int j = w*192 + jj;
      acc += pl[j] * p.wfc[(size_t)j*OUTC + tile*64 + lane];
    }
    red[w*64 + lane] = acc;
    __syncthreads();
    if (t < 64)
      p.out[(size_t)b*OUTC + tile*64 + t] =
          red[t] + red[64+t] + red[128+t] + red[192+t] + p.bfc[tile*64 + t];
  }
}

extern "C" void kernel_launch(void* const* d_in, const int* in_sizes, int n_in,
                              void* d_out, int out_size, void* d_ws, size_t ws_size,
                              hipStream_t stream) {
  float* ws = (float*)d_ws;
  P prm;
  prm.x   = (const float*)d_in[0];
  prm.wqg = (const float*)d_in[7];
  prm.bqg = (const float*)d_in[8];
  prm.wkg = (const float*)d_in[9];
  prm.bkg = (const float*)d_in[10];
  prm.wvg = (const float*)d_in[11];
  prm.bvg = (const float*)d_in[12];
  prm.wo  = (const float*)d_in[13];
  prm.bo  = (const float*)d_in[14];
  prm.wp  = (const float*)d_in[15];
  prm.bp  = (const float*)d_in[16];
  prm.wfc = (const float*)d_in[17];
  prm.bfc = (const float*)d_in[18];
  prm.bar       = (unsigned*)d_ws;   // 64 floats reserved
  prm.qpart     = ws + 64;           // 12288
  prm.qb        = ws + 12352;        // 24 (pad 32)
  prm.l         = ws + 12384;        // 24 (pad 32)
  prm.qw        = ws + 12416;        // 18432
  prm.out0acc   = ws + 30848;        // 1536 ┐
  prm.attnraw   = ws + 32384;        // 1536 │ zeroed by block 72 in S2
  prm.pooledraw = ws + 33920;        // 1536 ┘
  prm.part      = ws + 35456;        // 2*64*12*768 = 1179648
  prm.out       = (float*)d_out;

  kFused<<<dim3(NBLK), dim3(256), 0, stream>>>(prm);
}

// Round 7
// 218.989 us; speedup vs baseline: 3.8576x; 2.7888x over previous
//
#include <hip/hip_runtime.h>

#define BB 2
#define SS 4096
#define DM 768
#define NH 12
#define OUTC 512
#define QSCALE 0.125f

__device__ __forceinline__ float wave_sum64(float v) {
#pragma unroll
  for (int o = 32; o > 0; o >>= 1) v += __shfl_xor(v, o, 64);
  return v;
}

// K1: grid 97. blk<96: (h,b,js) — compute qg[h] redundantly per js, fold wkg
// slice into qw; js==0 also computes qb and zeroes l. blk==96 zeroes out0acc.
__global__ __launch_bounds__(256) void k1(const float* __restrict__ x,
    const float* __restrict__ wqg, const float* __restrict__ bqg,
    const float* __restrict__ wkg, const float* __restrict__ bkg,
    float* __restrict__ qw, float* __restrict__ qb, float* __restrict__ l,
    float* __restrict__ out0acc) {
  int blk = blockIdx.x, t = threadIdx.x;
  if (blk == 96) {
    for (int i = t; i < BB*DM; i += 256) out0acc[i] = 0.f;
    return;
  }
  int h = blk % 12, r = blk / 12, b = r & 1, js = r >> 1;
  __shared__ float x0[DM];
  __shared__ float red[256];
  __shared__ float qg[64];
  for (int i = t; i < DM; i += 256) x0[i] = x[(size_t)b*SS*DM + i];
  __syncthreads();
  int d = t & 63, g = t >> 6;
  float acc = 0.f;
  for (int i = g*192; i < g*192 + 192; ++i)
    acc += x0[i] * wqg[(size_t)i*DM + h*64 + d];
  red[t] = acc;
  __syncthreads();
  if (t < 64)
    qg[t] = (red[t] + red[64+t] + red[128+t] + red[192+t] + bqg[h*64 + t]) * QSCALE;
  __syncthreads();
  if (js == 0 && t < 64) {
    float qbv = wave_sum64(qg[t] * bkg[h*64 + t]);
    if (t == 0) { qb[b*NH + h] = qbv; l[b*NH + h] = 0.f; }
  }
  if (t < 192) {
    int j = js*192 + t;
    const float4* wr = (const float4*)wkg + (size_t)j*192 + h*16;
    const float4* qg4 = (const float4*)qg;
    float a = 0.f;
#pragma unroll
    for (int q = 0; q < 16; ++q) {
      float4 wv = wr[q], qv = qg4[q];
      a += wv.x*qv.x + wv.y*qv.y + wv.z*qv.z + wv.w*qv.w;
    }
    qw[((size_t)b*NH + h)*DM + j] = a;
  }
}

// K2: grid 512 = chunk(64) x hg(4) x b(2). Fused scores+exp+l+weighted row-sum
// partials for 3 heads over a 64-row chunk.
__global__ __launch_bounds__(256) void k2(const float* __restrict__ x,
    const float* __restrict__ qw, const float* __restrict__ qb,
    float* __restrict__ l, float* __restrict__ part) {
  int blk = blockIdx.x;
  int c = blk & 63, hg = (blk >> 6) & 3, b = blk >> 8;
  int t = threadIdx.x, lane = t & 63, w = t >> 6;
  __shared__ float qwl[3*DM];
  __shared__ float pl[64*3];
  __shared__ float qbl[3];
  const float* qwsrc = qw + ((size_t)b*NH + hg*3)*DM;
  for (int i = t; i < 3*DM; i += 256) qwl[i] = qwsrc[i];
  if (t < 3) qbl[t] = qb[b*NH + hg*3 + t];
  __syncthreads();
  const size_t xbase = ((size_t)b*SS + (size_t)c*64)*DM;
  const float4* x4 = (const float4*)(x + xbase);
  const float4* qw4 = (const float4*)qwl;
  float lacc = 0.f;
#pragma unroll
  for (int batch = 0; batch < 4; ++batch) {
    int sl = w*16 + batch*4;
    float acc[4][3] = {};
#pragma unroll
    for (int k = 0; k < 3; ++k) {
      int jq = k*64 + lane;
      float4 xf[4];
#pragma unroll
      for (int si = 0; si < 4; ++si) xf[si] = x4[(size_t)(sl + si)*192 + jq];
#pragma unroll
      for (int hh = 0; hh < 3; ++hh) {
        float4 qv = qw4[hh*192 + jq];
#pragma unroll
        for (int si = 0; si < 4; ++si)
          acc[si][hh] += xf[si].x*qv.x + xf[si].y*qv.y + xf[si].z*qv.z + xf[si].w*qv.w;
      }
    }
    float preg = 0.f;
#pragma unroll
    for (int si = 0; si < 4; ++si)
#pragma unroll
      for (int hh = 0; hh < 3; ++hh) {
        float r = wave_sum64(acc[si][hh]);
        float pp = __expf(r + qbl[hh]);
        if (lane == hh) lacc += pp;
        if (lane == si*3 + hh) preg = pp;
      }
    if (lane < 12) pl[(sl + lane/3)*3 + (lane % 3)] = preg;
  }
  if (lane < 3) atomicAdd(&l[b*NH + hg*3 + lane], lacc);
  __syncthreads();
  float a2[3][3] = {};
  for (int s = 0; s < 64; ++s) {
    float pv0 = pl[s*3], pv1 = pl[s*3+1], pv2 = pl[s*3+2];
    float xv0 = x[xbase + (size_t)s*DM + t];
    float xv1 = x[xbase + (size_t)s*DM + t + 256];
    float xv2 = x[xbase + (size_t)s*DM + t + 512];
    a2[0][0] += pv0*xv0; a2[0][1] += pv0*xv1; a2[0][2] += pv0*xv2;
    a2[1][0] += pv1*xv0; a2[1][1] += pv1*xv1; a2[1][2] += pv1*xv2;
    a2[2][0] += pv2*xv0; a2[2][1] += pv2*xv1; a2[2][2] += pv2*xv2;
  }
  float* dst = part + ((size_t)(b*64 + c)*NH + hg*3)*DM;
#pragma unroll
  for (int hh = 0; hh < 3; ++hh)
#pragma unroll
    for (int i = 0; i < 3; ++i) dst[hh*DM + t + 256*i] = a2[hh][i];
}

// K3: grid 288 = js(12) x h(12) x b(2). Reduce partials over 64 chunks, /l,
// then out0acc[b, h*64+:] += xwn_slice . wvg_slice (atomic, 12 adds/address).
__global__ __launch_bounds__(256) void k3(const float* __restrict__ part,
    const float* __restrict__ l, const float* __restrict__ wvg,
    float* __restrict__ out0acc) {
  int blk = blockIdx.x;
  int js = blk % 12, r = blk / 12, h = r % 12, b = r / 12;
  int t = threadIdx.x, lane = t & 63, w = t >> 6;
  __shared__ float red[256];
  __shared__ float xs[64];
  float s = 0.f;
  for (int cc = 0; cc < 16; ++cc) {
    int c = w*16 + cc;
    s += part[((size_t)(b*64 + c)*NH + h)*DM + js*64 + lane];
  }
  red[t] = s;
  __syncthreads();
  if (t < 64)
    xs[t] = (red[t] + red[64+t] + red[128+t] + red[192+t]) / l[b*NH + h];
  __syncthreads();
  float acc = 0.f;
#pragma unroll
  for (int q = 0; q < 16; ++q)
    acc += xs[w*16 + q] * wvg[(size_t)(js*64 + w*16 + q)*DM + h*64 + lane];
  red[t] = acc;
  __syncthreads();
  if (t < 64)
    atomicAdd(&out0acc[b*DM + h*64 + t],
              red[t] + red[64+t] + red[128+t] + red[192+t]);
}

// K4: grid 2 (one per b) x 768 threads. Full tail: attn = (out0+bvg)@wo+bo;
// pooled = tanh(attn@wp+bp); out = pooled@wfc+bfc. j-split partials + LDS reduce.
__global__ __launch_bounds__(768) void k4(const float* __restrict__ out0acc,
    const float* __restrict__ bvg, const float* __restrict__ wo,
    const float* __restrict__ bo, const float* __restrict__ wp,
    const float* __restrict__ bp, const float* __restrict__ wfc,
    const float* __restrict__ bfc, float* __restrict__ out) {
  int b = blockIdx.x, t = threadIdx.x;
  __shared__ float vin[DM];
  __shared__ float red[4*DM];     // also reused as red6[6*512]
  __shared__ float v2[DM];
  vin[t] = out0acc[b*DM + t] + bvg[t];
  __syncthreads();
  int jg = t / 192, cq = t % 192;
  // mv1: wo
  {
    float4 pa = {0,0,0,0};
    const float4* W4 = (const float4*)wo;
    for (int jj = 0; jj < 192; ++jj) {
      int j = jg*192 + jj;
      float sv = vin[j];
      float4 wv = W4[(size_t)j*192 + cq];
      pa.x += sv*wv.x; pa.y += sv*wv.y; pa.z += sv*wv.z; pa.w += sv*wv.w;
    }
    red[jg*DM + 4*cq+0] = pa.x; red[jg*DM + 4*cq+1] = pa.y;
    red[jg*DM + 4*cq+2] = pa.z; red[jg*DM + 4*cq+3] = pa.w;
  }
  __syncthreads();
  v2[t] = red[t] + red[DM+t] + red[2*DM+t] + red[3*DM+t] + bo[t];
  __syncthreads();
  // mv2: wp
  {
    float4 pa = {0,0,0,0};
    const float4* W4 = (const float4*)wp;
    for (int jj = 0; jj < 192; ++jj) {
      int j = jg*192 + jj;
      float sv = v2[j];
      float4 wv = W4[(size_t)j*192 + cq];
      pa.x += sv*wv.x; pa.y += sv*wv.y; pa.z += sv*wv.z; pa.w += sv*wv.w;
    }
    red[jg*DM + 4*cq+0] = pa.x; red[jg*DM + 4*cq+1] = pa.y;
    red[jg*DM + 4*cq+2] = pa.z; red[jg*DM + 4*cq+3] = pa.w;
  }
  __syncthreads();
  vin[t] = tanhf(red[t] + red[DM+t] + red[2*DM+t] + red[3*DM+t] + bp[t]);
  __syncthreads();
  // mv3: wfc (768x512), 6 jg-groups x 128 float4-cols
  {
    int jg6 = t / 128, cq6 = t % 128;
    float4 pa = {0,0,0,0};
    const float4* W4 = (const float4*)wfc;
    for (int jj = 0; jj < 128; ++jj) {
      int j = jg6*128 + jj;
      float sv = vin[j];
      float4 wv = W4[(size_t)j*128 + cq6];
      pa.x += sv*wv.x; pa.y += sv*wv.y; pa.z += sv*wv.z; pa.w += sv*wv.w;
    }
    red[jg6*OUTC + 4*cq6+0] = pa.x; red[jg6*OUTC + 4*cq6+1] = pa.y;
    red[jg6*OUTC + 4*cq6+2] = pa.z; red[jg6*OUTC + 4*cq6+3] = pa.w;
  }
  __syncthreads();
  if (t < OUTC) {
    float r = bfc[t];
#pragma unroll
    for (int g = 0; g < 6; ++g) r += red[g*OUTC + t];
    out[(size_t)b*OUTC + t] = r;
  }
}

extern "C" void kernel_launch(void* const* d_in, const int* in_sizes, int n_in,
                              void* d_out, int out_size, void* d_ws, size_t ws_size,
                              hipStream_t stream) {
  const float* x   = (const float*)d_in[0];
  const float* wqg = (const float*)d_in[7];
  const float* bqg = (const float*)d_in[8];
  const float* wkg = (const float*)d_in[9];
  const float* bkg = (const float*)d_in[10];
  const float* wvg = (const float*)d_in[11];
  const float* bvg = (const float*)d_in[12];
  const float* wo  = (const float*)d_in[13];
  const float* bo  = (const float*)d_in[14];
  const float* wp  = (const float*)d_in[15];
  const float* bp  = (const float*)d_in[16];
  const float* wfc = (const float*)d_in[17];
  const float* bfc = (const float*)d_in[18];

  float* ws      = (float*)d_ws;
  float* qw      = ws;            // 18432
  float* qb      = ws + 18432;    // 24 (pad 32)
  float* l       = ws + 18464;    // 24 (pad 32)
  float* out0acc = ws + 18496;    // 1536
  float* part    = ws + 20480;    // 2*64*12*768 = 1179648

  k1<<<dim3(97),  256, 0, stream>>>(x, wqg, bqg, wkg, bkg, qw, qb, l, out0acc);
  k2<<<dim3(512), 256, 0, stream>>>(x, qw, qb, l, part);
  k3<<<dim3(288), 256, 0, stream>>>(part, l, wvg, out0acc);
  k4<<<dim3(2),   768, 0, stream>>>(out0acc, bvg, wo, bo, wp, bp, wfc, bfc,
                                    (float*)d_out);
}